// Round 7
// baseline (551.452 us; speedup 1.0000x reference)
//
#include <hip/hip_runtime.h>
#include <hip/hip_bf16.h>

// Problem constants (B=4, S=2048, H=2048, E=8, K=2)
#define T_TOK 8192
#define H_DIM 2048
#define NE 8
#define NT (H_DIM / 64)

typedef float f32x4 __attribute__((ext_vector_type(4)));
typedef short s16x8 __attribute__((ext_vector_type(8)));

typedef __attribute__((address_space(3))) unsigned int lds_uint;
typedef __attribute__((address_space(1))) const unsigned int glob_uint;

static __device__ __forceinline__ void async_ld16(const void* g, void* l) {
    // 64 lanes x 16B: global per-lane address -> LDS (wave-uniform base + lane*16)
    __builtin_amdgcn_global_load_lds((glob_uint*)g, (lds_uint*)l, 16, 0, 0);
}

static __device__ __forceinline__ unsigned short f32_to_bf16(float f) {
    unsigned int u = __builtin_bit_cast(unsigned int, f);
    unsigned int r = (u + 0x7FFFu + ((u >> 16) & 1u)) >> 16;
    return (unsigned short)r;
}

// ---------------------------------------------------------------------------
// Kernel 1: convert W fp32 -> bf16, zero expert counters. (R0-exact; runs at
// ~5.2 TB/s ≈ its 402 MB roofline. R6 proved fusing this into the GEMM costs
// more inside the MFMA schedule (+93 us) than it saves here (-77 us).)
// ---------------------------------------------------------------------------
__global__ __launch_bounds__(256) void prep_kernel(
        const float* __restrict__ w, unsigned short* __restrict__ wb,
        int* __restrict__ cnt) {
    const long g = (long)blockIdx.x * 256 + threadIdx.x;
    if (g < NE) cnt[g] = 0;
    const long nt = (long)gridDim.x * 256;
    const long N_W4 = (long)NE * H_DIM * H_DIM / 4;  // 8,388,608 float4
    const float4* w4 = (const float4*)w;
    ushort4* wb4 = (ushort4*)wb;
    for (long i = g; i < N_W4; i += nt) {
        float4 v = w4[i];
        wb4[i] = make_ushort4(f32_to_bf16(v.x), f32_to_bf16(v.y),
                              f32_to_bf16(v.z), f32_to_bf16(v.w));
    }
}

// ---------------------------------------------------------------------------
// Kernel 2: router (R0-exact). 512 blocks x 16 tokens, gate staged in LDS,
// fused X fp32->bf16, fp32 logits, softmax-free top-2, per-block aggregated
// list append.
// ---------------------------------------------------------------------------
__global__ __launch_bounds__(256) void router_kernel(
        const float* __restrict__ x, const float* __restrict__ gate,
        unsigned short* __restrict__ xb, float* __restrict__ logits,
        int* __restrict__ cnt, int* __restrict__ list, float* __restrict__ wl) {
    __shared__ float4 gs[NE * H_DIM / 4];  // 64 KiB
    __shared__ int aExp[32];
    __shared__ float aW[32];
    const float4* g4 = (const float4*)gate;
    for (int i = threadIdx.x; i < NE * H_DIM / 4; i += 256) gs[i] = g4[i];
    __syncthreads();

    const int wave = threadIdx.x >> 6, lane = threadIdx.x & 63;

    for (int it = 0; it < 4; ++it) {
        const int tok = wave * 4 + it;               // 0..15 within block
        const int t = blockIdx.x * 16 + tok;
        const float4* xr = (const float4*)(x + (long)t * H_DIM);
        ushort4* xw = (ushort4*)(xb + (long)t * H_DIM);
        float acc[NE];
#pragma unroll
        for (int e = 0; e < NE; ++e) acc[e] = 0.f;
#pragma unroll
        for (int i = 0; i < 8; ++i) {
            float4 xv = xr[i * 64 + lane];
            xw[i * 64 + lane] = make_ushort4(f32_to_bf16(xv.x), f32_to_bf16(xv.y),
                                             f32_to_bf16(xv.z), f32_to_bf16(xv.w));
#pragma unroll
            for (int e = 0; e < NE; ++e) {
                float4 gv = gs[e * 512 + i * 64 + lane];
                acc[e] += xv.x * gv.x + xv.y * gv.y + xv.z * gv.z + xv.w * gv.w;
            }
        }
#pragma unroll
        for (int e = 0; e < NE; ++e)
#pragma unroll
            for (int off = 32; off > 0; off >>= 1)
                acc[e] += __shfl_xor(acc[e], off, 64);

        if (lane == 0) {
            float l0 = -1e30f; int i0 = 0;
#pragma unroll
            for (int e = 0; e < NE; ++e)
                if (acc[e] > l0) { l0 = acc[e]; i0 = e; }
            float l1 = -1e30f; int i1 = 0;
#pragma unroll
            for (int e = 0; e < NE; ++e)
                if (e != i0 && acc[e] > l1) { l1 = acc[e]; i1 = e; }
            float e1v = __expf(l1 - l0);
            float inv = 1.f / (1.f + e1v);
#pragma unroll
            for (int e = 0; e < NE; ++e) logits[(long)t * NE + e] = acc[e];
            aExp[tok * 2] = i0;     aW[tok * 2] = inv;
            aExp[tok * 2 + 1] = i1; aW[tok * 2 + 1] = e1v * inv;
        }
    }
    __syncthreads();

    if (threadIdx.x < NE) {
        const int e = threadIdx.x;
        int c = 0;
#pragma unroll
        for (int k = 0; k < 32; ++k) c += (aExp[k] == e);
        if (c) {
            int pos = atomicAdd(&cnt[e], c);
            for (int k = 0; k < 32; ++k)
                if (aExp[k] == e) {
                    list[e * T_TOK + pos] = blockIdx.x * 16 + (k >> 1);
                    wl[e * T_TOK + pos] = aW[k];
                    ++pos;
                }
        }
    }
}

// ---------------------------------------------------------------------------
// Kernel 3: grouped expert GEMM. R0 structure (128x128 tile, BK=64, 4 waves
// of 4x4 16x16x32 bf16 MFMA, XOR-swizzled LDS, identity XCD map) with TWO
// changes:
//  (1) A-only double buffer + counted vmcnt. A is the gathered (scattered,
//      L2-missy) operand whose latency R0's __syncthreads (vmcnt(0) drain)
//      exposed every K-tile. Per tile boundary: [s_barrier WAR] -> issue
//      B(t) into Bs (single buf) + A(t+1) into As[(t+1)&1] -> vmcnt(4)
//      (drains A(t)+B(t), oldest 8; leaves A(t+1) in flight across the
//      whole compute phase) -> [s_barrier RAW] -> compute. Same 2 barriers
//      per tile as R0; only B's L2-friendly dense-read latency remains
//      exposed. LDS 49.3 KiB -> 3 blocks/CU (R0's measured residency).
//      R2 (dbuf BOTH, 65 KiB, 2 blocks/CU) lost to occupancy; this keeps it.
//  (2) rt-major block order: working blocks (rt < ~17 of 64) occupy the
//      first ~2176 contiguous block ids -> no empty-block dispatch bubbles.
// ---------------------------------------------------------------------------
__global__ __launch_bounds__(256, 4) void moe_gemm(
        const unsigned short* __restrict__ xb, const unsigned short* __restrict__ wb,
        const int* __restrict__ cnt, const int* __restrict__ list,
        const float* __restrict__ wl, float* __restrict__ out) {
    __shared__ uint4 As[2][1024];  // 2 x (128 rows x 64 bf16) = 32 KiB
    __shared__ uint4 Bs[1024];     // 16 KiB
    __shared__ int tIdx[128];
    __shared__ float tw[128];

    // rt-major mapping: all working blocks first.
    const int bx = blockIdx.x;
    const int rt = bx >> 7;          // 0..63 row tiles (slowest)
    const int e  = (bx >> 4) & 7;    // expert
    const int ct = bx & 15;          // 16 col tiles
    const int n = cnt[e];
    const int row0 = rt << 7;
    if (row0 >= n) return;
    const int rv = min(128, n - row0);

    const int tid = threadIdx.x;
    if (tid < 128) {
        if (tid < rv) {
            tIdx[tid] = list[e * T_TOK + row0 + tid];
            tw[tid]   = wl[e * T_TOK + row0 + tid];
        } else { tIdx[tid] = 0; tw[tid] = 0.f; }
    }
    __syncthreads();

    const int wave = tid >> 6, lane = tid & 63;
    const int wm = (wave >> 1) << 6;   // 0 / 64
    const int wn = (wave & 1) << 6;    // 0 / 64
    const int quad = lane >> 4, l16 = lane & 15;

    f32x4 acc[4][4];
#pragma unroll
    for (int i = 0; i < 4; ++i)
#pragma unroll
        for (int j = 0; j < 4; ++j) acc[i][j] = (f32x4){0.f, 0.f, 0.f, 0.f};

    // Per-lane global sources for async staging: phys chunk p = i*256+tid
    const unsigned short* aSrc[4];
    const unsigned short* bSrc[4];
    const long wbase = (long)e * H_DIM * H_DIM + (long)(ct * 128) * H_DIM;
#pragma unroll
    for (int i = 0; i < 4; ++i) {
        const int p = i * 256 + tid;
        const int r = p >> 3;
        const int c = (p & 7) ^ (r & 7);   // logical k-chunk for this phys slot
        aSrc[i] = xb + (long)tIdx[r] * H_DIM + c * 8;
        bSrc[i] = wb + wbase + (long)r * H_DIM + c * 8;
    }
    const int dst0 = wave * 64;

    // Prologue: issue A(0) into As[0] (4 loads in flight).
#pragma unroll
    for (int i = 0; i < 4; ++i) async_ld16(aSrc[i], &As[0][i * 256 + dst0]);

    for (int t = 0; t < NT; ++t) {
        const int k0 = t << 6;
        // WAR guard: all waves' reads of Bs(t-1) / As[(t+1)&1] (== t-1's
        // parity) retired before restaging. (First iter: trivially safe.)
        __builtin_amdgcn_s_barrier();

        // Stage B(t) into the single B buffer.
#pragma unroll
        for (int i = 0; i < 4; ++i)
            async_ld16(bSrc[i] + k0, &Bs[i * 256 + dst0]);
        if (t + 1 < NT) {
            // Prefetch A(t+1); its gather latency spans compute(t).
#pragma unroll
            for (int i = 0; i < 4; ++i)
                async_ld16(aSrc[i] + k0 + 64, &As[(t + 1) & 1][i * 256 + dst0]);
            // Outstanding: A(t)(4, oldest) + B(t)(4) + A(t+1)(4) = 12.
            // Wait to 4: A(t), B(t) retired; A(t+1) stays in flight.
            asm volatile("s_waitcnt vmcnt(4)" ::: "memory");
        } else {
            asm volatile("s_waitcnt vmcnt(0)" ::: "memory");
        }
        __builtin_amdgcn_s_barrier();   // tile t staged for all waves

        // Compute tile t from As[t&1] / Bs.
        const s16x8* Ap = (const s16x8*)&As[t & 1][0];
        const s16x8* Bp = (const s16x8*)&Bs[0];
#pragma unroll
        for (int ks = 0; ks < 2; ++ks) {
            s16x8 af[4], bfr[4];
            const int kc = ks * 4 + quad;
#pragma unroll
            for (int i = 0; i < 4; ++i) {
                int r = wm + i * 16 + l16;
                af[i] = Ap[(r << 3) | (kc ^ (r & 7))];
            }
#pragma unroll
            for (int j = 0; j < 4; ++j) {
                int d = wn + j * 16 + l16;
                bfr[j] = Bp[(d << 3) | (kc ^ (d & 7))];
            }
#pragma unroll
            for (int i = 0; i < 4; ++i)
#pragma unroll
                for (int j = 0; j < 4; ++j)
                    acc[i][j] = __builtin_amdgcn_mfma_f32_16x16x32_bf16(
                        af[i], bfr[j], acc[i][j], 0, 0, 0);
        }
    }

    // Epilogue: C/D layout col = lane&15, row = quad*4 + reg.
    const int colbase = ct * 128 + wn;
#pragma unroll
    for (int i = 0; i < 4; ++i) {
        const int rbase = wm + i * 16 + quad * 4;
#pragma unroll
        for (int jr = 0; jr < 4; ++jr) {
            const int r = rbase + jr;
            if (r < rv) {
                const float wgt = tw[r];
                const long orow = (long)tIdx[r] * H_DIM + colbase;
#pragma unroll
                for (int j = 0; j < 4; ++j)
                    atomicAdd(&out[orow + j * 16 + l16], acc[i][j][jr] * wgt);
            }
        }
    }
}

// ---------------------------------------------------------------------------
extern "C" void kernel_launch(void* const* d_in, const int* in_sizes, int n_in,
                              void* d_out, int out_size, void* d_ws, size_t ws_size,
                              hipStream_t stream) {
    (void)in_sizes; (void)n_in; (void)out_size; (void)ws_size;
    const float* x    = (const float*)d_in[0];   // [T, H] fp32
    const float* gate = (const float*)d_in[1];   // [E, H] fp32
    const float* w    = (const float*)d_in[2];   // [E, H, H] fp32

    float* out    = (float*)d_out;                       // [T, H]
    float* logits = out + (size_t)T_TOK * H_DIM;         // [T, E]

    char* ws = (char*)d_ws;
    unsigned short* xb = (unsigned short*)(ws);                 // 33,554,432 B
    unsigned short* wb = (unsigned short*)(ws + 33554432);      // 67,108,864 B
    int*   cnt  = (int*)(ws + 100663296);                       // 32 B
    int*   list = (int*)(ws + 100663328);                       // 262,144 B
    float* wl   = (float*)(ws + 100925472);                     // 262,144 B

    hipMemsetAsync(out, 0, (size_t)T_TOK * H_DIM * sizeof(float), stream);
    prep_kernel<<<2048, 256, 0, stream>>>(w, wb, cnt);
    router_kernel<<<512, 256, 0, stream>>>(x, gate, xb, logits, cnt, list, wl);
    moe_gemm<<<8192, 256, 0, stream>>>(xb, wb, cnt, list, wl, out);
}